// Round 7
// baseline (32.835 us; speedup 1.0000x reference)
//
#include <hip/hip_runtime.h>
#include <hip/hip_fp16.h>

#define BATCH  1024
#define NVARS  2048
#define N_OUT  4096

#define WIN_COLS 8                      // columns per window
#define NWIN     (BATCH / WIN_COLS)     // 128 windows
#define WBYTES   (NVARS * WIN_COLS * 2) // 32 KB per window (fp16)
#define CHUNK    256                    // outputs per block
#define NCHUNK   (N_OUT / CHUNK)        // 16

__device__ __forceinline__ __half2 u2h2(unsigned u) {
    union { unsigned u; __half2 h; } c; c.u = u; return c.h;
}
__device__ __forceinline__ unsigned h22u(__half2 h) {
    union { unsigned u; __half2 h; } c; c.h = h; return c.u;
}

// ---------------- prep: x -> window-major fp16 AND flatten tree ----------------
// xh2: [128 win][2048 row][8 cols] fp16.  byte(win,row,col)=win*32768+row*16+col*2
// T[i*8+m] = leafA | leafB<<16, leaf = sel<<11 | row.  sel:0->0,1->1,2->x,3->1-x
__global__ void prep_kernel(const float* __restrict__ x,
                            const int2* __restrict__ idx0,
                            const int2* __restrict__ idx1,
                            const int2* __restrict__ idx2,
                            const int2* __restrict__ idx3,
                            unsigned* __restrict__ T,
                            char* __restrict__ xh2)
{
    const int gtid = blockIdx.x * blockDim.x + threadIdx.x;   // 262144 threads
    const int r  = gtid >> 7;          // row 0..2047
    const int c8 = gtid & 127;         // window 0..127

    {   // 8 f32 of (row r, cols c8*8..c8*8+7) -> 16 B fp16 into window c8
        const float4* x4 = (const float4*)x;
        float4 a = x4[(size_t)r * 256 + c8 * 2];
        float4 b = x4[(size_t)r * 256 + c8 * 2 + 1];
        uint4 w;
        w.x = h22u(__floats2half2_rn(a.x, a.y));
        w.y = h22u(__floats2half2_rn(a.z, a.w));
        w.z = h22u(__floats2half2_rn(b.x, b.y));
        w.w = h22u(__floats2half2_rn(b.z, b.w));
        *reinterpret_cast<uint4*>(xh2 + (size_t)c8 * WBYTES + r * 16) = w;
    }

    if (gtid < N_OUT) {
        const int i = gtid;
        int2 p3 = idx3[i];
        int n = 0;
        #pragma unroll
        for (int t = 0; t < 2; ++t) {
            int2 p2 = idx2[t ? p3.y : p3.x];
            #pragma unroll
            for (int u = 0; u < 2; ++u) {
                int2 p1 = idx1[u ? p2.y : p2.x];
                #pragma unroll
                for (int v = 0; v < 2; ++v) {
                    int2 p0 = idx0[v ? p1.y : p1.x];
                    unsigned w = 0;
                    #pragma unroll
                    for (int e = 0; e < 2; ++e) {
                        int k = e ? p0.y : p0.x;
                        unsigned code;
                        if (k < 2) code = (unsigned)k << 11;
                        else       code = ((2u + (k & 1)) << 11) | ((unsigned)(k - 2) >> 1);
                        w |= code << (16 * e);
                    }
                    T[(size_t)i * 8 + n] = w;
                    ++n;
                }
            }
        }
    }
}

__device__ __forceinline__ void sel2sc(unsigned sel, unsigned& s, unsigned& c) {
    // half2 constants: 1.0h2 = 0x3C003C00, -1.0h2 = 0xBC00BC00
    c = (sel & 1u) ? 0x3C003C00u : 0u;
    s = (sel == 2u) ? 0x3C003C00u : (sel == 3u) ? 0xBC00BC00u : 0u;
}

// ---------------- main: LDS-staged 8-col window, 256 outputs per block --------
// bx = win*16 + chunk  ->  XCD = bx%8 = chunk%8 (sibling windows of an out-line
// share an XCD so partial-line stores merge in L2).
__global__ __launch_bounds__(256) void knowledge_main(
    const char* __restrict__ xh2,
    const uint4* __restrict__ T4,     // 2 x uint4 per output (8 packed pair-words)
    float* __restrict__ out)
{
    __shared__ char xs[WBYTES];       // 32 KB: row r at byte r*16 (8 fp16 cols)

    const int bx    = blockIdx.x;     // 2048 blocks
    const int tid   = threadIdx.x;
    const int win   = bx >> 4;        // 0..127
    const int chunk = bx & 15;        // 0..15

    // ---- stage window: 32 KB contiguous, 8 x (64 lanes x 16 B) per wave ----
    {
        const char* src = xh2 + (size_t)win * WBYTES;
        const int w    = tid >> 6;
        const int lane = tid & 63;
        #pragma unroll
        for (int p = 0; p < 8; ++p) {
            const int off = w * 8192 + p * 1024 + lane * 16;
            *reinterpret_cast<uint4*>(xs + off) =
                *reinterpret_cast<const uint4*>(src + off);
        }
    }
    __syncthreads();

    const int cp = tid & 3;           // col-pair 0..3 (2 cols = 4 B)
    const int ol = tid >> 2;          // output-in-pass 0..63

    #pragma unroll
    for (int pass = 0; pass < 4; ++pass) {
        const int o = chunk * CHUNK + pass * 64 + ol;
        uint4 t0 = T4[(size_t)o * 2];
        uint4 t1 = T4[(size_t)o * 2 + 1];
        const unsigned tw[8] = {t0.x, t0.y, t0.z, t0.w, t1.x, t1.y, t1.z, t1.w};

        // 16 LDS gathers (banks (r*4+cp)%32: ~2-way conflict, free)
        __half2 av[8], bv[8];
        #pragma unroll
        for (int m = 0; m < 8; ++m) {
            unsigned w = tw[m];
            av[m] = *reinterpret_cast<const __half2*>(
                        xs + ((w & 0x7FFu) << 4) + cp * 4);
            bv[m] = *reinterpret_cast<const __half2*>(
                        xs + (((w >> 16) & 0x7FFu) << 4) + cp * 4);
        }

        float2 accf = make_float2(0.f, 0.f);
        #pragma unroll
        for (int a3 = 0; a3 < 2; ++a3) {                 // top SumLayer
            __half2 prod2;
            #pragma unroll
            for (int a2 = 0; a2 < 2; ++a2) {             // ProductLayer
                __half2 sum1;
                #pragma unroll
                for (int a1 = 0; a1 < 2; ++a1) {         // SumLayer
                    const int m = a3 * 4 + a2 * 2 + a1;
                    unsigned w = tw[m];
                    unsigned sa, ca, sb, cb;
                    sel2sc((w >> 11) & 3u, sa, ca);
                    sel2sc((w >> 27) & 3u, sb, cb);
                    __half2 va = __hfma2(av[m], u2h2(sa), u2h2(ca));
                    __half2 vb = __hfma2(bv[m], u2h2(sb), u2h2(cb));
                    __half2 p  = __hmul2(va, vb);        // leaf product
                    sum1 = (a1 == 0) ? p : __hadd2(sum1, p);
                }
                prod2 = (a2 == 0) ? sum1 : __hmul2(prod2, sum1);
            }
            float2 pf = __half22float2(prod2);
            accf.x += pf.x; accf.y += pf.y;
        }

        *reinterpret_cast<float2*>(out + (size_t)o * BATCH + win * 8 + cp * 2) = accf;
    }
}

// ---------------- fallback (round-1 kernel) if ws too small ----------------
__device__ __forceinline__ float Hval(int k, const float* __restrict__ x, int b) {
    if (k < 2) return (float)k;
    float v = x[((k - 2) >> 1) * BATCH + b];
    return (k & 1) ? 1.0f - v : v;
}

__global__ __launch_bounds__(256) void knowledge_fused_kernel(
    const float* __restrict__ x,
    const int2* __restrict__ idx0,
    const int2* __restrict__ idx1,
    const int2* __restrict__ idx2,
    const int2* __restrict__ idx3,
    float* __restrict__ out)
{
    const int i = blockIdx.x;
    const int b = blockIdx.y * blockDim.x + threadIdx.x;
    const int2 p3 = idx3[i];
    float acc3 = 0.0f;
    #pragma unroll
    for (int t = 0; t < 2; ++t) {
        const int2 p2 = idx2[t ? p3.y : p3.x];
        float prod2 = 1.0f;
        #pragma unroll
        for (int u = 0; u < 2; ++u) {
            const int2 p1 = idx1[u ? p2.y : p2.x];
            float sum1 = 0.0f;
            #pragma unroll
            for (int v = 0; v < 2; ++v) {
                const int2 p0 = idx0[v ? p1.y : p1.x];
                sum1 += Hval(p0.x, x, b) * Hval(p0.y, x, b);
            }
            prod2 *= sum1;
        }
        acc3 += prod2;
    }
    out[(size_t)i * BATCH + b] = acc3;
}

extern "C" void kernel_launch(void* const* d_in, const int* in_sizes, int n_in,
                              void* d_out, int out_size, void* d_ws, size_t ws_size,
                              hipStream_t stream) {
    const float* x    = (const float*)d_in[0];
    const int2*  idx0 = (const int2*)d_in[1];
    const int2*  idx1 = (const int2*)d_in[2];
    const int2*  idx2 = (const int2*)d_in[3];
    const int2*  idx3 = (const int2*)d_in[4];
    float* out = (float*)d_out;

    const size_t t_bytes   = (size_t)N_OUT * 8 * sizeof(unsigned);   // 128 KB
    const size_t xh2_bytes = (size_t)NWIN * WBYTES;                  // 4 MB
    if (ws_size >= t_bytes + xh2_bytes) {
        unsigned* T   = (unsigned*)d_ws;
        char*     xh2 = (char*)d_ws + t_bytes;
        prep_kernel<<<(NVARS * BATCH / 8) / 256, 256, 0, stream>>>(
            x, idx0, idx1, idx2, idx3, T, xh2);
        knowledge_main<<<NWIN * NCHUNK, 256, 0, stream>>>(
            xh2, (const uint4*)T, out);
    } else {
        dim3 grid(N_OUT, BATCH / 256);
        knowledge_fused_kernel<<<grid, 256, 0, stream>>>(x, idx0, idx1, idx2, idx3, out);
    }
}

// Round 8
// 28.183 us; speedup vs baseline: 1.1651x; 1.1651x over previous
//
#include <hip/hip_runtime.h>
#include <hip/hip_fp16.h>

#define BATCH  1024
#define NVARS  2048
#define N_OUT  4096

#define W8BYTES (NVARS * 16)     // 32 KB per 8-col window
#define NW8     (BATCH / 8)      // 128 windows

typedef float f32x4 __attribute__((ext_vector_type(4)));

__device__ __forceinline__ __half2 u2h2(unsigned u) {
    union { unsigned u; __half2 h; } c; c.u = u; return c.h;
}
__device__ __forceinline__ unsigned h22u(__half2 h) {
    union { unsigned u; __half2 h; } c; c.h = h; return c.u;
}
__device__ __forceinline__ void sel2sc(unsigned sel, unsigned& s, unsigned& c) {
    // half2 constants: 1.0h2 = 0x3C003C00, -1.0h2 = 0xBC00BC00
    c = (sel & 1u) ? 0x3C003C00u : 0u;
    s = (sel == 2u) ? 0x3C003C00u : (sel == 3u) ? 0xBC00BC00u : 0u;
}

// ---------------- prep: LDS-tile transpose to window-major fp16 + T-flatten ----
// xh2: [128 w08][2048 row][8 cols] fp16; byte(w08,r) = w08*32768 + r*16
// T[i*8+m] = leafA | leafB<<16, leaf = sel<<11 | row. sel:0->0,1->1,2->x,3->1-x
__global__ __launch_bounds__(256) void prep_kernel(
    const float* __restrict__ x,
    const int2* __restrict__ idx0,
    const int2* __restrict__ idx1,
    const int2* __restrict__ idx2,
    const int2* __restrict__ idx3,
    unsigned* __restrict__ T,
    char* __restrict__ xh2)
{
    __shared__ char tile[64 * 272];    // 64 rows x 128 cols fp16, 272B padded rows

    const int bid = blockIdx.x;        // 256 blocks
    const int tid = threadIdx.x;
    const int rt  = bid >> 3;          // row tile 0..31
    const int ct  = bid & 7;           // col tile 0..7 (128 cols each)
    const int r0  = rt * 64;

    // ---- T-flatten on blocks 0..15 ----
    if (bid < 16) {
        const int i = bid * 256 + tid;
        int2 p3 = idx3[i];
        int n = 0;
        #pragma unroll
        for (int t = 0; t < 2; ++t) {
            int2 p2 = idx2[t ? p3.y : p3.x];
            #pragma unroll
            for (int u = 0; u < 2; ++u) {
                int2 p1 = idx1[u ? p2.y : p2.x];
                #pragma unroll
                for (int v = 0; v < 2; ++v) {
                    int2 p0 = idx0[v ? p1.y : p1.x];
                    unsigned w = 0;
                    #pragma unroll
                    for (int e = 0; e < 2; ++e) {
                        int k = e ? p0.y : p0.x;
                        unsigned code;
                        if (k < 2) code = (unsigned)k << 11;
                        else       code = ((2u + (k & 1)) << 11) | ((unsigned)(k - 2) >> 1);
                        w |= code << (16 * e);
                    }
                    T[(size_t)i * 8 + n] = w;
                    ++n;
                }
            }
        }
    }

    // ---- phase A: coalesced read of 64 rows x 128 cols, cvt fp16 into tile ----
    {
        const int r_l = tid >> 5;      // 0..7
        const int c4  = tid & 31;      // 0..31 float4 units
        #pragma unroll
        for (int q = 0; q < 8; ++q) {
            const int rr = q * 8 + r_l;                 // tile row 0..63
            float4 v = ((const float4*)x)[(size_t)(r0 + rr) * 256 + ct * 32 + c4];
            unsigned h0 = h22u(__floats2half2_rn(v.x, v.y));
            unsigned h1 = h22u(__floats2half2_rn(v.z, v.w));
            unsigned* p = (unsigned*)(tile + rr * 272 + c4 * 8);
            p[0] = h0; p[1] = h1;
        }
    }
    __syncthreads();

    // ---- phase B: write window-major, 1 KB contiguous per wave ----
    {
        const int r2 = tid & 63;
        const int wl = tid >> 6;       // 0..3
        #pragma unroll
        for (int pp = 0; pp < 4; ++pp) {
            const int w08l = pp * 4 + wl;              // 0..15
            uint4 v = *(const uint4*)(tile + r2 * 272 + w08l * 16);
            const int w08 = ct * 16 + w08l;
            *(uint4*)(xh2 + (size_t)w08 * W8BYTES + (r0 + r2) * 16) = v;
        }
    }
}

// ---------------- main: L1-resident window gathers, full-line NT stores --------
// 256 blocks x 512 threads (1 block/CU). block = (oc = b>>5 : 512 outputs,
// cb = b&31 : 32 cols). 4 phases, each over one 32 KB window (L1-resident).
// oc-siblings share XCD (b%8 = cb%8) so window fills hit the same L2.
__global__ __launch_bounds__(512) void knowledge_main(
    const char* __restrict__ xh2,
    const uint4* __restrict__ T4,     // 2 x uint4 per output (8 packed pair-words)
    float* __restrict__ out)
{
    __shared__ char st[4][64 * 144];  // 36 KB store-transpose buffers

    const int b   = blockIdx.x;       // 256
    const int tid = threadIdx.x;      // 512
    const int cb  = b & 31;
    const int oc  = b >> 5;
    const int o   = oc * 512 + tid;

    uint4 t0 = T4[(size_t)o * 2];
    uint4 t1 = T4[(size_t)o * 2 + 1];
    const unsigned tw[8] = {t0.x, t0.y, t0.z, t0.w, t1.x, t1.y, t1.z, t1.w};

    int offA[8], offB[8];
    unsigned sA[8], cA[8], sB[8], cB[8];
    #pragma unroll
    for (int m = 0; m < 8; ++m) {
        offA[m] = (int)((tw[m] & 0x7FFu) << 4);
        offB[m] = (int)(((tw[m] >> 16) & 0x7FFu) << 4);
        sel2sc((tw[m] >> 11) & 3u, sA[m], cA[m]);
        sel2sc((tw[m] >> 27) & 3u, sB[m], cB[m]);
    }

    float acc[32];

    #pragma unroll
    for (int p = 0; p < 4; ++p) {
        const char* base = xh2 + (size_t)(cb * 4 + p) * W8BYTES;

        // coalesced prefetch sweep: 512 thr x 64 B = whole window into L1
        {
            const uint4* src = (const uint4*)base + tid * 4;
            uint4 pa = src[0], pb = src[1], pc = src[2], pd = src[3];
            asm volatile("" :: "v"(pa.x), "v"(pa.y), "v"(pa.z), "v"(pa.w),
                               "v"(pb.x), "v"(pb.y), "v"(pb.z), "v"(pb.w),
                               "v"(pc.x), "v"(pc.y), "v"(pc.z), "v"(pc.w),
                               "v"(pd.x), "v"(pd.y), "v"(pd.z), "v"(pd.w));
        }

        // 16 gathers of 16 B, L1 hits
        uint4 Av[8], Bv[8];
        #pragma unroll
        for (int m = 0; m < 8; ++m) {
            Av[m] = *(const uint4*)(base + offA[m]);
            Bv[m] = *(const uint4*)(base + offB[m]);
        }

        float accp[8];
        #pragma unroll
        for (int k2 = 0; k2 < 8; ++k2) accp[k2] = 0.f;

        #pragma unroll
        for (int a3 = 0; a3 < 2; ++a3) {                 // top SumLayer
            __half2 prod2[4];
            #pragma unroll
            for (int a2 = 0; a2 < 2; ++a2) {             // ProductLayer
                __half2 sum1[4];
                #pragma unroll
                for (int a1 = 0; a1 < 2; ++a1) {         // SumLayer
                    const int m = a3 * 4 + a2 * 2 + a1;
                    const unsigned aw[4] = {Av[m].x, Av[m].y, Av[m].z, Av[m].w};
                    const unsigned bw[4] = {Bv[m].x, Bv[m].y, Bv[m].z, Bv[m].w};
                    #pragma unroll
                    for (int k = 0; k < 4; ++k) {
                        __half2 va = __hfma2(u2h2(aw[k]), u2h2(sA[m]), u2h2(cA[m]));
                        __half2 vb = __hfma2(u2h2(bw[k]), u2h2(sB[m]), u2h2(cB[m]));
                        __half2 pr = __hmul2(va, vb);    // leaf product
                        sum1[k] = (a1 == 0) ? pr : __hadd2(sum1[k], pr);
                    }
                }
                #pragma unroll
                for (int k = 0; k < 4; ++k)
                    prod2[k] = (a2 == 0) ? sum1[k] : __hmul2(prod2[k], sum1[k]);
            }
            #pragma unroll
            for (int k = 0; k < 4; ++k) {
                float2 pf = __half22float2(prod2[k]);
                accp[k * 2]     += pf.x;
                accp[k * 2 + 1] += pf.y;
            }
        }
        #pragma unroll
        for (int k2 = 0; k2 < 8; ++k2) acc[p * 8 + k2] = accp[k2];
    }

    // ---- store: per-wave LDS transpose -> 8x128B full-line NT stores ----
    const int w    = tid >> 6;
    const int lane = tid & 63;
    char* buf = st[w & 3];
    const size_t orow0 = (size_t)(oc * 512 + w * 64);

    auto dump = [&]() {
        #pragma unroll
        for (int k = 0; k < 8; ++k) {
            f32x4 v = {acc[k * 4], acc[k * 4 + 1], acc[k * 4 + 2], acc[k * 4 + 3]};
            *reinterpret_cast<f32x4*>(buf + lane * 144 + k * 16) = v;
        }
        #pragma unroll
        for (int j = 0; j < 8; ++j) {
            const int r     = j * 8 + (lane >> 3);
            const int piece = lane & 7;
            f32x4 v = *reinterpret_cast<const f32x4*>(buf + r * 144 + piece * 16);
            float* dst = out + (orow0 + r) * BATCH + cb * 32 + piece * 4;
            __builtin_nontemporal_store(v, reinterpret_cast<f32x4*>(dst));
        }
    };
    if (w < 4) dump();
    __syncthreads();
    if (w >= 4) dump();
}

// ---------------- fallback (round-1 kernel) if ws too small ----------------
__device__ __forceinline__ float Hval(int k, const float* __restrict__ x, int b) {
    if (k < 2) return (float)k;
    float v = x[((k - 2) >> 1) * BATCH + b];
    return (k & 1) ? 1.0f - v : v;
}

__global__ __launch_bounds__(256) void knowledge_fused_kernel(
    const float* __restrict__ x,
    const int2* __restrict__ idx0,
    const int2* __restrict__ idx1,
    const int2* __restrict__ idx2,
    const int2* __restrict__ idx3,
    float* __restrict__ out)
{
    const int i = blockIdx.x;
    const int b = blockIdx.y * blockDim.x + threadIdx.x;
    const int2 p3 = idx3[i];
    float acc3 = 0.0f;
    #pragma unroll
    for (int t = 0; t < 2; ++t) {
        const int2 p2 = idx2[t ? p3.y : p3.x];
        float prod2 = 1.0f;
        #pragma unroll
        for (int u = 0; u < 2; ++u) {
            const int2 p1 = idx1[u ? p2.y : p2.x];
            float sum1 = 0.0f;
            #pragma unroll
            for (int v = 0; v < 2; ++v) {
                const int2 p0 = idx0[v ? p1.y : p1.x];
                sum1 += Hval(p0.x, x, b) * Hval(p0.y, x, b);
            }
            prod2 *= sum1;
        }
        acc3 += prod2;
    }
    out[(size_t)i * BATCH + b] = acc3;
}

extern "C" void kernel_launch(void* const* d_in, const int* in_sizes, int n_in,
                              void* d_out, int out_size, void* d_ws, size_t ws_size,
                              hipStream_t stream) {
    const float* x    = (const float*)d_in[0];
    const int2*  idx0 = (const int2*)d_in[1];
    const int2*  idx1 = (const int2*)d_in[2];
    const int2*  idx2 = (const int2*)d_in[3];
    const int2*  idx3 = (const int2*)d_in[4];
    float* out = (float*)d_out;

    const size_t t_bytes   = (size_t)N_OUT * 8 * sizeof(unsigned);   // 128 KB
    const size_t xh2_bytes = (size_t)NW8 * W8BYTES;                  // 4 MB
    if (ws_size >= t_bytes + xh2_bytes) {
        unsigned* T   = (unsigned*)d_ws;
        char*     xh2 = (char*)d_ws + t_bytes;
        prep_kernel<<<256, 256, 0, stream>>>(x, idx0, idx1, idx2, idx3, T, xh2);
        knowledge_main<<<256, 512, 0, stream>>>(xh2, (const uint4*)T, out);
    } else {
        dim3 grid(N_OUT, BATCH / 256);
        knowledge_fused_kernel<<<grid, 256, 0, stream>>>(x, idx0, idx1, idx2, idx3, out);
    }
}